// Round 1
// 578.359 us; speedup vs baseline: 1.0263x; 1.0263x over previous
//
#include <hip/hip_runtime.h>

// Problem constants (fixed shapes from setup_inputs)
#define P_TOT   2048        // 8*256 positions
#define V       32000
#define D       100
#define DPAD    128         // padded N for 8 n-tiles of 16
#define TS      16          // positions per block (16 = one MFMA M-tile)
#define VSPLIT  10          // vocab splits
#define KB      3200        // V / VSPLIT
#define VC      128         // chunk columns
#define NCHUNK  25          // KB / VC
#define ASTRIDE 136         // VC + 8 (bf16 units) -> 272B rows
#define BSTRIDE 136
#define BTILE_BYTES (DPAD * BSTRIDE * 2)   // 34816 B per (vs,ch) Wt tile

typedef __attribute__((ext_vector_type(8))) short short8;
typedef __attribute__((ext_vector_type(4))) float floatx4;

static __device__ __forceinline__ unsigned short f2bf(float x) {
    // round-to-nearest-even f32 -> bf16 (no NaN inputs here)
    unsigned u = __float_as_uint(x);
    u += 0x7FFFu + ((u >> 16) & 1u);
    return (unsigned short)(u >> 16);
}

static __device__ __forceinline__ void gload_lds16(const void* g, void* l) {
    // async global->LDS DMA, 16B per lane; LDS dest = uniform base + lane*16
    __builtin_amdgcn_global_load_lds(
        (const __attribute__((address_space(1))) unsigned int*)g,
        (__attribute__((address_space(3))) unsigned int*)l, 16, 0, 0);
}

// ---------------------------------------------------------------------------
// Kernel 0: W[32000][100] f32 -> Wtp[vs][ch][128][136] bf16 tiles.
// Each (vs,ch) tile's linear image IS the padded LDS layout k_main wants,
// so k_main can stage it with linear global_load_lds. Pad cols 128..135 and
// pad rows d>=100 are zero (never read by the MFMA K-range anyway).
// ---------------------------------------------------------------------------
__global__ __launch_bounds__(256)
void k_prep(const float* __restrict__ W, unsigned short* __restrict__ Wtp) {
    __shared__ float tile[VC * 101];   // [vl][d], stride 101 (coprime w/ 32 banks)
    const int ch = blockIdx.x, vs = blockIdx.y;
    const int vbase = vs * KB + ch * VC;
    const int tid = threadIdx.x;
    const float* src = W + (size_t)vbase * D;
    for (int idx = tid; idx < VC * D; idx += 256) {       // 12800 contiguous f32
        int vl = idx / D, d = idx - vl * D;
        tile[vl * 101 + d] = src[idx];
    }
    __syncthreads();
    unsigned short* dst = Wtp + (size_t)(vs * NCHUNK + ch) * (DPAD * BSTRIDE);
    for (int idx = tid; idx < DPAD * BSTRIDE; idx += 256) {   // 17408 bf16, contiguous
        int d = idx / BSTRIDE, e = idx - d * BSTRIDE;
        float v = (d < D && e < VC) ? tile[e * 101 + d] : 0.0f;
        dst[idx] = f2bf(v);
    }
}

// ---------------------------------------------------------------------------
// Kernel 1: fused online-softmax + gumbel + argmax + bf16 MFMA partial GEMM
// grid (128, 10): blockIdx.x = position tile (16 rows), blockIdx.y = vocab split
// 16 q-lanes per row, 8 elements each. 4 waves x 2 N-tiles of the MFMA output.
// ---------------------------------------------------------------------------
__global__ __launch_bounds__(256, 4)
void k_main(const float* __restrict__ logits, const float* __restrict__ gum,
            const unsigned short* __restrict__ Wtp,
            float* __restrict__ Epart, float* __restrict__ stats) {
    __shared__ __align__(16) unsigned short Abuf[TS * ASTRIDE];    //  4352 B
    __shared__ __align__(16) unsigned short Bbuf[DPAD * BSTRIDE];  // 34816 B
    __shared__ __align__(16) float alphaS[TS];
    __shared__ float m2run[TS], s2run[TS], amaxv[TS];
    __shared__ int amaxi[TS];

    const int tid   = threadIdx.x;
    const int r     = tid >> 4;        // row 0..15
    const int q     = tid & 15;        // 16 lanes per row
    const int lane  = tid & 63;
    const int w     = tid >> 6;        // wave 0..3 -> N cols w*32 .. w*32+31
    const int stile = blockIdx.x;
    const int vs    = blockIdx.y;

    const int grow = stile * TS + r;
    const size_t rowbase = (size_t)grow * V + (size_t)vs * KB;

    if (tid < TS) {
        m2run[tid] = -1e30f; s2run[tid] = 0.0f;
        amaxv[tid] = -1e30f; amaxi[tid] = 0;
    }

    float m1 = -1e30f, sA = 0.0f, sB = 0.0f;   // online stats for log_softmax(logits)
    floatx4 acc[2];
    acc[0] = (floatx4){0.f, 0.f, 0.f, 0.f};
    acc[1] = (floatx4){0.f, 0.f, 0.f, 0.f};

    const float* lbase = logits + rowbase + q * 8;
    const float* ubase = gum    + rowbase + q * 8;

    // preload chunk 0 into current regs
    float4 cl0 = *(const float4*)(lbase);
    float4 cl1 = *(const float4*)(lbase + 4);
    float4 cu0 = *(const float4*)(ubase);
    float4 cu1 = *(const float4*)(ubase + 4);

    const char* wsrc = (const char*)Wtp + (size_t)vs * NCHUNK * BTILE_BYTES
                     + (size_t)lane * 16;

    for (int ch = 0; ch < NCHUNK; ++ch) {
        const int cbase = ch * VC;

        __syncthreads();   // barrier A: prev MFMA done with Abuf/Bbuf/alpha

        // ---- async stage Wt tile -> Bbuf (linear DMA, hidden under VALU) ----
        {
            const char* src = wsrc + (size_t)ch * BTILE_BYTES;
            char* dstb = (char*)Bbuf;
            #pragma unroll
            for (int it = 0; it < 8; ++it) {
                int k = it * 4 + w;                      // 32 wave-instructions
                gload_lds16(src + k * 1024, dstb + k * 1024);
            }
            if (w < 2) {                                 // 34816 = 34 * 1024
                int k = 32 + w;
                gload_lds16(src + k * 1024, dstb + k * 1024);
            }
        }

        // ---- prefetch next-chunk logits/u into regs (drains at barrier B) ----
        float4 nl0, nl1, nu0, nu1;
        if (ch + 1 < NCHUNK) {
            const float* lp = lbase + cbase + VC;
            const float* up = ubase + cbase + VC;
            nl0 = *(const float4*)(lp);
            nl1 = *(const float4*)(lp + 4);
            nu0 = *(const float4*)(up);
            nu1 = *(const float4*)(up + 4);
        }

        // ---- compute g, z from current regs ----
        float lg[8], zz[8];
        {
            float la[8] = {cl0.x, cl0.y, cl0.z, cl0.w, cl1.x, cl1.y, cl1.z, cl1.w};
            float ua[8] = {cu0.x, cu0.y, cu0.z, cu0.w, cu1.x, cu1.y, cu1.z, cu1.w};
            #pragma unroll
            for (int j = 0; j < 8; ++j) {
                lg[j] = la[j];
                // precise logf: feeds argmax (must match JAX ordering)
                float g = -logf(-logf(ua[j] + 1e-20f) + 1e-20f);
                zz[j] = la[j] + g;
            }
        }

        // ---- online (m1, sum e, sum t*e) for entropy ----
        {
            float cm = lg[0];
            #pragma unroll
            for (int j = 1; j < 8; ++j) cm = fmaxf(cm, lg[j]);
            float m1n = fmaxf(m1, cm);
            float sc = __expf(m1 - m1n);                    // 0 on first chunk
            sB = (sB + sA * (m1 - m1n)) * sc;
            sA = sA * sc;
            m1 = m1n;
            #pragma unroll
            for (int j = 0; j < 8; ++j) {
                float t = lg[j] - m1;
                float e = __expf(t);
                sA += e; sB += t * e;
            }
        }

        // ---- chunk z max + first-index argmax, reduce over 16 q-lanes ----
        float cmv = -1e30f; int cmi = 0;
        #pragma unroll
        for (int j = 0; j < 8; ++j) {
            int gidx = vs * KB + cbase + q * 8 + j;   // ascending in j
            if (zz[j] > cmv) { cmv = zz[j]; cmi = gidx; }
        }
        #pragma unroll
        for (int m = 1; m < 16; m <<= 1) {
            float ov = __shfl_xor(cmv, m, 64);
            int   oi = __shfl_xor(cmi, m, 64);
            if (ov > cmv || (ov == cmv && oi < cmi)) { cmv = ov; cmi = oi; }
        }

        // ---- p~ = exp(z - m2new), write bf16 A-tile, update row state ----
        float m2old = m2run[r];            // same-wave lockstep vs q==0 writer
        float m2new = fmaxf(m2old, cmv);
        float csum = 0.0f;
        unsigned short pb[8];
        #pragma unroll
        for (int j = 0; j < 8; ++j) {
            float p = __expf(zz[j] - m2new);
            csum += p;
            pb[j] = f2bf(p);
        }
        *(ushort4*)(&Abuf[r * ASTRIDE + q * 8])     = make_ushort4(pb[0], pb[1], pb[2], pb[3]);
        *(ushort4*)(&Abuf[r * ASTRIDE + q * 8 + 4]) = make_ushort4(pb[4], pb[5], pb[6], pb[7]);
        #pragma unroll
        for (int m = 1; m < 16; m <<= 1) csum += __shfl_xor(csum, m, 64);
        if (q == 0) {
            float al = __expf(m2old - m2new);
            alphaS[r] = al;
            s2run[r] = s2run[r] * al + csum;
            m2run[r] = m2new;
            if (cmv > amaxv[r]) { amaxv[r] = cmv; amaxi[r] = cmi; }
        }

        __syncthreads();   // barrier B: Abuf ready, Bbuf DMA + prefetch drained

        // ---- rescale accumulators, MFMA over 4 k-steps x 2 n-tiles ----
        floatx4 al4 = *(const floatx4*)(&alphaS[(lane >> 4) << 2]);
        #pragma unroll
        for (int nt = 0; nt < 2; ++nt) {
            acc[nt][0] *= al4[0]; acc[nt][1] *= al4[1];
            acc[nt][2] *= al4[2]; acc[nt][3] *= al4[3];
        }
        const int ka0 = (lane >> 4) << 3;  // quad*8
        const unsigned short* arow = &Abuf[(lane & 15) * ASTRIDE + ka0];
        #pragma unroll
        for (int ks = 0; ks < 4; ++ks) {
            short8 a = *(const short8*)(arow + ks * 32);
            #pragma unroll
            for (int nt = 0; nt < 2; ++nt) {
                const unsigned short* brow =
                    &Bbuf[(w * 32 + nt * 16 + (lane & 15)) * BSTRIDE + ka0 + ks * 32];
                short8 b = *(const short8*)brow;
                acc[nt] = __builtin_amdgcn_mfma_f32_16x16x32_bf16(a, b, acc[nt], 0, 0, 0);
            }
        }

        if (ch + 1 < NCHUNK) { cl0 = nl0; cl1 = nl1; cu0 = nu0; cu1 = nu1; }
    }

    // ---- final: merge entropy stats across 16 q-lanes, write partials ----
    #pragma unroll
    for (int m = 1; m < 16; m <<= 1) {
        float om = __shfl_xor(m1, m, 64);
        float oA = __shfl_xor(sA, m, 64);
        float oB = __shfl_xor(sB, m, 64);
        float mn = fmaxf(m1, om);
        float ea = __expf(m1 - mn), eb = __expf(om - mn);
        sB = (sB + sA * (m1 - mn)) * ea + (oB + oA * (om - mn)) * eb;
        sA = sA * ea + oA * eb;
        m1 = mn;
    }
    if (q == 0) {
        float* st = stats + ((size_t)grow * VSPLIT + vs) * 8;
        st[0] = m1; st[1] = sA; st[2] = sB;
        st[3] = m2run[r]; st[4] = s2run[r];
        st[5] = amaxv[r]; st[6] = __int_as_float(amaxi[r]); st[7] = 0.0f;
    }
    #pragma unroll
    for (int nt = 0; nt < 2; ++nt) {
        int n = w * 32 + nt * 16 + (lane & 15);
        if (n < D) {
            #pragma unroll
            for (int i = 0; i < 4; ++i) {
                int row = ((lane >> 4) << 2) + i;
                int pos = stile * TS + row;
                Epart[((size_t)pos * VSPLIT + vs) * D + n] = acc[nt][i];
            }
        }
    }
}

// ---------------------------------------------------------------------------
// Kernel 2: combine V-splits per position; write obf_word + obf_word_emb + ent
// ---------------------------------------------------------------------------
__global__ __launch_bounds__(128)
void k_combine(const float* __restrict__ stats, const float* __restrict__ Epart,
               const float* __restrict__ W, const int* __restrict__ inp,
               const int* __restrict__ msk, float* __restrict__ out,
               float* __restrict__ entbuf) {
    const int pos = blockIdx.x;
    const int t = threadIdx.x;
    const float* st = stats + (size_t)pos * VSPLIT * 8;

    // redundant uniform combine on all threads (scalar-cached)
    float m1 = -1e30f, sA = 0.0f, sB = 0.0f, m2g = -1e30f;
    float bestv = -1e30f; int besti = 0;
    #pragma unroll
    for (int p = 0; p < VSPLIT; ++p) {
        const float* s = st + p * 8;
        float om = s[0], oA = s[1], oB = s[2];
        float mn = fmaxf(m1, om);
        float ea = __expf(m1 - mn), eb = __expf(om - mn);
        sB = (sB + sA * (m1 - mn)) * ea + (oB + oA * (om - mn)) * eb;
        sA = sA * ea + oA * eb;
        m1 = mn;
        m2g = fmaxf(m2g, s[3]);
        float av = s[5];
        if (av > bestv) { bestv = av; besti = __float_as_int(s[6]); }  // split order = index order
    }
    float beta[VSPLIT];
    float s2g = 0.0f;
    #pragma unroll
    for (int p = 0; p < VSPLIT; ++p) {
        beta[p] = __expf(st[p*8 + 3] - m2g);
        s2g += st[p*8 + 4] * beta[p];
    }

    const int iw = inp[pos];
    const bool mk = msk[pos] != 0;
    const bool safe = besti != iw;

    if (t == 0) {
        int obf = mk ? (safe ? besti : 0) : iw;
        out[pos] = (float)obf;
        float ent = sB / sA - logf(sA);       // sum lp*exp(lp), shift-invariant
        entbuf[pos] = mk ? ent : 0.0f;
    }
    if (t < D) {
        float e = 0.0f;
        const float* ep = Epart + (size_t)pos * VSPLIT * D + t;
        #pragma unroll
        for (int p = 0; p < VSPLIT; ++p) e += ep[(size_t)p * D] * beta[p];
        e /= s2g;                              // sampled_emb[t]
        float val;
        if (mk) val = safe ? e : W[t];         // W[0][t] = unk_emb
        else    val = W[(size_t)iw * D + t];   // base_emb
        out[P_TOT + (size_t)pos * D + t] = val;
    }
}

// ---------------------------------------------------------------------------
// Kernel 3: ent_loss scalar
// ---------------------------------------------------------------------------
__global__ __launch_bounds__(256)
void k_final(const float* __restrict__ entbuf, const int* __restrict__ msk,
             float* __restrict__ out) {
    __shared__ float se[4], sm[4];
    const int t = threadIdx.x;
    float e = 0.0f, m = 0.0f;
    for (int i = t; i < P_TOT; i += 256) {
        e += entbuf[i];
        m += (float)msk[i];
    }
    #pragma unroll
    for (int k = 32; k >= 1; k >>= 1) {
        e += __shfl_down(e, k, 64);
        m += __shfl_down(m, k, 64);
    }
    if ((t & 63) == 0) { se[t >> 6] = e; sm[t >> 6] = m; }
    __syncthreads();
    if (t == 0) {
        float te = se[0] + se[1] + se[2] + se[3];
        float tm = sm[0] + sm[1] + sm[2] + sm[3];
        out[P_TOT + (size_t)P_TOT * D] = te / (tm * (float)V);
    }
}

// ---------------------------------------------------------------------------
extern "C" void kernel_launch(void* const* d_in, const int* in_sizes, int n_in,
                              void* d_out, int out_size, void* d_ws, size_t ws_size,
                              hipStream_t stream) {
    const float* logits = (const float*)d_in[0];
    const float* gum    = (const float*)d_in[1];
    const int*   inp    = (const int*)d_in[2];
    const int*   msk    = (const int*)d_in[3];
    const float* W      = (const float*)d_in[4];
    float* out = (float*)d_out;

    char* ws = (char*)d_ws;
    unsigned short* Wtp = (unsigned short*)ws;            // 10*25*128*136*2 = 8,704,000 B
    float* Epart  = (float*)(ws + 8704000);               // 2048*10*100*4 = 8,192,000 B
    float* stats  = (float*)(ws + 16896000);              // 2048*10*8*4  =   655,360 B
    float* entbuf = (float*)(ws + 17551360);              // 2048*4       =     8,192 B

    k_prep<<<dim3(NCHUNK, VSPLIT), 256, 0, stream>>>(W, Wtp);
    dim3 g1(P_TOT / TS, VSPLIT);
    k_main<<<g1, 256, 0, stream>>>(logits, gum, Wtp, Epart, stats);
    k_combine<<<P_TOT, 128, 0, stream>>>(stats, Epart, W, inp, msk, out, entbuf);
    k_final<<<1, 256, 0, stream>>>(entbuf, msk, out);
}

// Round 3
// 568.289 us; speedup vs baseline: 1.0445x; 1.0177x over previous
//
#include <hip/hip_runtime.h>

// Problem constants (fixed shapes from setup_inputs)
#define P_TOT   2048        // 8*256 positions
#define V       32000
#define D       100
#define DPAD    128         // padded N for 8 n-tiles of 16
#define TS      16          // positions per block (one MFMA M-tile)
#define VSPLIT  10          // vocab splits
#define KB      3200        // V / VSPLIT
#define VC      64          // chunk columns (2 MFMA k-steps)
#define NCHUNK  50          // KB / VC
#define STRIDE  68          // ushorts/row: 136B rows, 8B-aligned, bank-stride 2dw
#define BTILE   (DPAD * STRIDE)     // 8704 ushorts = 17408 B per (vs,ch) tile
#define NSTILE  (P_TOT / TS)        // 128

typedef __attribute__((ext_vector_type(8))) short short8;
typedef __attribute__((ext_vector_type(4))) short short4v;
typedef __attribute__((ext_vector_type(4))) float floatx4;

static __device__ __forceinline__ unsigned short f2bf(float x) {
    // round-to-nearest-even f32 -> bf16 (no NaN inputs here)
    unsigned u = __float_as_uint(x);
    u += 0x7FFFu + ((u >> 16) & 1u);
    return (unsigned short)(u >> 16);
}

static __device__ __forceinline__ unsigned cvt_pk_bf16(float lo, float hi) {
    // packed f32x2 -> bf16x2 (RNE); no builtin on gfx950, use asm (guide T12)
    unsigned r;
    asm("v_cvt_pk_bf16_f32 %0, %1, %2" : "=v"(r) : "v"(lo), "v"(hi));
    return r;
}

static __device__ __forceinline__ void gload_lds16(const void* g, void* l) {
    // async global->LDS DMA, 16B per lane; LDS dest = uniform base + lane*16
    __builtin_amdgcn_global_load_lds(
        (const __attribute__((address_space(1))) unsigned int*)g,
        (__attribute__((address_space(3))) unsigned int*)l, 16, 0, 0);
}

static __device__ __forceinline__ short8 lds_frag(const unsigned short* p) {
    // two ds_read_b64 (rows are 8B-aligned at STRIDE=68; b128 would misalign)
    short4v lo = *(const short4v*)p;
    short4v hi = *(const short4v*)(p + 4);
    short8 v = {lo[0], lo[1], lo[2], lo[3], hi[0], hi[1], hi[2], hi[3]};
    return v;
}

// ---------------------------------------------------------------------------
// Kernel 0: W[32000][100] f32 -> Wtp[vs][ch][128][68] bf16 tiles.
// Each (vs,ch) tile's linear image IS the LDS layout k_main wants, so k_main
// stages it with linear global_load_lds. Pad cols 64..67 / rows d>=100 zero.
// ---------------------------------------------------------------------------
__global__ __launch_bounds__(256)
void k_prep(const float* __restrict__ W, unsigned short* __restrict__ Wtp) {
    __shared__ float tile[VC * 101];   // [vl][d], stride 101 (coprime w/ banks)
    const int ch = blockIdx.x, vs = blockIdx.y;
    const int tid = threadIdx.x;
    const float* src = W + (size_t)(vs * KB + ch * VC) * D;   // 64 rows x 100 f32
    for (int idx = tid; idx < VC * D; idx += 256) {           // contiguous load
        int vl = idx / D, d = idx - vl * D;
        tile[vl * 101 + d] = src[idx];
    }
    __syncthreads();
    unsigned short* dst = Wtp + (size_t)(vs * NCHUNK + ch) * BTILE;
    for (int idx = tid; idx < BTILE; idx += 256) {            // contiguous store
        int d = idx / STRIDE, e = idx - d * STRIDE;
        float v = (d < D && e < VC) ? tile[e * 101 + d] : 0.0f;
        dst[idx] = f2bf(v);
    }
}

// ---------------------------------------------------------------------------
// Kernel 1: fused online-softmax + gumbel + argmax + bf16 MFMA partial GEMM
// 1-D grid of 1280 blocks; XCD-chunked decode (bid%8 = XCD gets a contiguous
// work range -> each XCD's L2 holds <=2 Wt panels). LDS ~19.9KB + VGPR<=64
// -> 8 blocks/CU capacity -> ALL 1280 blocks resident (no 2nd launch wave).
// Argmax: cheap __logf z for all elems; ONE precise logf for the per-thread
// cheap winner; delta-guard (1e-4 >> 2x max cheap error ~1.1e-5) falls back
// to full precise recompute -> selected (cmv,cmi) is bit-identical to the
// all-precise kernel for every input. p~/entropy paths are tolerance-bound.
// ---------------------------------------------------------------------------
__global__ __launch_bounds__(256, 8)
void k_main(const float* __restrict__ logits, const float* __restrict__ gum,
            const unsigned short* __restrict__ Wtp,
            float* __restrict__ Epart, float* __restrict__ stats) {
    __shared__ __align__(16) unsigned short Abuf[TS * STRIDE];    //  2176 B
    __shared__ __align__(16) unsigned short Bbuf[DPAD * STRIDE];  // 17408 B
    __shared__ __align__(16) float alphaS[TS];
    __shared__ float m2run[TS], s2run[TS], amaxv[TS];
    __shared__ int amaxi[TS];

    const int tid   = threadIdx.x;
    const int r     = tid >> 4;        // row 0..15
    const int q     = tid & 15;        // 16 lanes per row, 4 cols each
    const int lane  = tid & 63;
    const int w     = tid >> 6;        // wave 0..3 -> N cols w*32 .. w*32+31

    // XCD-chunked bijective decode (1280 % 8 == 0)
    const int bid   = blockIdx.x;
    const int gidxb = (bid & 7) * (NSTILE * VSPLIT / 8) + (bid >> 3);
    const int vs    = gidxb / NSTILE;
    const int stile = gidxb - vs * NSTILE;

    const int grow = stile * TS + r;
    const size_t rowbase = (size_t)grow * V + (size_t)vs * KB;

    if (tid < TS) {
        m2run[tid] = -1e30f; s2run[tid] = 0.0f;
        amaxv[tid] = -1e30f; amaxi[tid] = 0;
    }

    float m1 = -1e30f, sA = 0.0f, sB = 0.0f;   // online stats for log_softmax(logits)
    floatx4 acc[2];
    acc[0] = (floatx4){0.f, 0.f, 0.f, 0.f};
    acc[1] = (floatx4){0.f, 0.f, 0.f, 0.f};

    const float* lbase = logits + rowbase + q * 4;
    const float* ubase = gum    + rowbase + q * 4;

    // preload chunk 0 into current regs
    float4 cl = *(const float4*)(lbase);
    float4 cu = *(const float4*)(ubase);

    const char* wsrc = (const char*)Wtp + (size_t)vs * NCHUNK * (BTILE * 2)
                     + (size_t)lane * 16;

    for (int ch = 0; ch < NCHUNK; ++ch) {
        const int cbase = ch * VC;

        __syncthreads();   // barrier A: prev MFMA done with Abuf/Bbuf/alpha

        // ---- async stage Wt tile -> Bbuf (17 x 1KB linear DMA) ----
        {
            const char* src = wsrc + (size_t)ch * (BTILE * 2);
            char* dstb = (char*)Bbuf;
            #pragma unroll
            for (int it = 0; it < 4; ++it) {
                int k = it * 4 + w;
                gload_lds16(src + k * 1024, dstb + k * 1024);
            }
            if (w == 0) gload_lds16(src + 16 * 1024, dstb + 16 * 1024);
        }

        // ---- prefetch next-chunk logits/u into regs (drains at barrier B) ----
        float4 nl, nu;
        if (ch + 1 < NCHUNK) {
            nl = *(const float4*)(lbase + cbase + VC);
            nu = *(const float4*)(ubase + cbase + VC);
        }

        // ---- cheap z = lg + g~  (fast __logf; only winner needs precision) ----
        float lg[4] = {cl.x, cl.y, cl.z, cl.w};
        float ua[4] = {cu.x, cu.y, cu.z, cu.w};
        float zz[4];
        #pragma unroll
        for (int j = 0; j < 4; ++j) {
            float g = -__logf(-__logf(ua[j] + 1e-20f) + 1e-20f);
            zz[j] = lg[j] + g;
        }

        // ---- online (m1, sum e, sum t*e) for entropy (raw logits, exact) ----
        {
            float cm = fmaxf(fmaxf(lg[0], lg[1]), fmaxf(lg[2], lg[3]));
            float m1n = fmaxf(m1, cm);
            float sc = __expf(m1 - m1n);                    // 0 on first chunk
            sB = (sB + sA * (m1 - m1n)) * sc;
            sA = sA * sc;
            m1 = m1n;
            #pragma unroll
            for (int j = 0; j < 4; ++j) {
                float t = lg[j] - m1;
                float e = __expf(t);
                sA += e; sB += t * e;
            }
        }

        // ---- per-thread top-2 on cheap z; one precise eval for the winner ----
        float b1 = zz[0], b2 = -1e30f;
        int bj = 0;
        #pragma unroll
        for (int j = 1; j < 4; ++j) {
            bool gt = zz[j] > b1;
            b2 = gt ? b1 : fmaxf(b2, zz[j]);
            b1 = gt ? zz[j] : b1;
            bj = gt ? j : bj;
        }
        float cmv; int cmi;
        if (__builtin_expect(b2 > b1 - 1e-4f, 0)) {
            // contested: full precise recompute, ascending-index first-max
            cmv = -1e30f; cmi = 0;
            #pragma unroll
            for (int j = 0; j < 4; ++j) {
                float zp = lg[j] - logf(-logf(ua[j] + 1e-20f) + 1e-20f);
                if (zp > cmv) { cmv = zp; cmi = j; }
            }
        } else {
            float bu = ua[0], bl = lg[0];
            #pragma unroll
            for (int j = 1; j < 4; ++j) {
                bu = (bj == j) ? ua[j] : bu;
                bl = (bj == j) ? lg[j] : bl;
            }
            cmv = bl - logf(-logf(bu + 1e-20f) + 1e-20f);   // precise, once
            cmi = bj;
        }
        cmi += vs * KB + cbase + q * 4;

        // ---- cross-lane argmax (precise values), 16 q-lanes ----
        #pragma unroll
        for (int m = 1; m < 16; m <<= 1) {
            float ov = __shfl_xor(cmv, m, 64);
            int   oi = __shfl_xor(cmi, m, 64);
            if (ov > cmv || (ov == cmv && oi < cmi)) { cmv = ov; cmi = oi; }
        }

        // ---- p~ = exp(z - m2new) (bf16-bound: cheap z fine), A-tile write ----
        float m2old = m2run[r];            // same-wave lockstep vs q==0 writer
        float m2new = fmaxf(m2old, cmv);
        float p0 = __expf(zz[0] - m2new), p1 = __expf(zz[1] - m2new);
        float p2 = __expf(zz[2] - m2new), p3 = __expf(zz[3] - m2new);
        float csum = (p0 + p1) + (p2 + p3);
        {
            uint2 pk;
            pk.x = cvt_pk_bf16(p0, p1);
            pk.y = cvt_pk_bf16(p2, p3);
            *(uint2*)(&Abuf[r * STRIDE + q * 4]) = pk;   // ds_write_b64
        }
        #pragma unroll
        for (int m = 1; m < 16; m <<= 1) csum += __shfl_xor(csum, m, 64);
        if (q == 0) {
            float al = __expf(m2old - m2new);
            alphaS[r] = al;
            s2run[r] = s2run[r] * al + csum;
            m2run[r] = m2new;
            if (cmv > amaxv[r]) { amaxv[r] = cmv; amaxi[r] = cmi; }
        }

        __syncthreads();   // barrier B: Abuf ready, Bbuf DMA + prefetch drained

        // ---- rescale accumulators, MFMA over 2 k-steps x 2 n-tiles ----
        floatx4 al4 = *(const floatx4*)(&alphaS[(lane >> 4) << 2]);
        #pragma unroll
        for (int nt = 0; nt < 2; ++nt) {
            acc[nt][0] *= al4[0]; acc[nt][1] *= al4[1];
            acc[nt][2] *= al4[2]; acc[nt][3] *= al4[3];
        }
        const int ka0 = (lane >> 4) << 3;  // quad*8
        const unsigned short* arow = &Abuf[(lane & 15) * STRIDE + ka0];
        #pragma unroll
        for (int ks = 0; ks < 2; ++ks) {
            short8 a = lds_frag(arow + ks * 32);
            #pragma unroll
            for (int nt = 0; nt < 2; ++nt) {
                short8 b = lds_frag(
                    &Bbuf[(w * 32 + nt * 16 + (lane & 15)) * STRIDE + ka0 + ks * 32]);
                acc[nt] = __builtin_amdgcn_mfma_f32_16x16x32_bf16(a, b, acc[nt], 0, 0, 0);
            }
        }

        if (ch + 1 < NCHUNK) { cl = nl; cu = nu; }
    }

    // ---- final: merge entropy stats across 16 q-lanes, write partials ----
    #pragma unroll
    for (int m = 1; m < 16; m <<= 1) {
        float om = __shfl_xor(m1, m, 64);
        float oA = __shfl_xor(sA, m, 64);
        float oB = __shfl_xor(sB, m, 64);
        float mn = fmaxf(m1, om);
        float ea = __expf(m1 - mn), eb = __expf(om - mn);
        sB = (sB + sA * (m1 - mn)) * ea + (oB + oA * (om - mn)) * eb;
        sA = sA * ea + oA * eb;
        m1 = mn;
    }
    if (q == 0) {
        float* st = stats + ((size_t)grow * VSPLIT + vs) * 8;
        st[0] = m1; st[1] = sA; st[2] = sB;
        st[3] = m2run[r]; st[4] = s2run[r];
        st[5] = amaxv[r]; st[6] = __int_as_float(amaxi[r]); st[7] = 0.0f;
    }
    #pragma unroll
    for (int nt = 0; nt < 2; ++nt) {
        int n = w * 32 + nt * 16 + (lane & 15);
        if (n < D) {
            #pragma unroll
            for (int i = 0; i < 4; ++i) {
                int row = ((lane >> 4) << 2) + i;
                int pos = stile * TS + row;
                Epart[((size_t)pos * VSPLIT + vs) * D + n] = acc[nt][i];
            }
        }
    }
}

// ---------------------------------------------------------------------------
// Kernel 2: combine V-splits per position; write obf_word + obf_word_emb + ent
// ---------------------------------------------------------------------------
__global__ __launch_bounds__(128)
void k_combine(const float* __restrict__ stats, const float* __restrict__ Epart,
               const float* __restrict__ W, const int* __restrict__ inp,
               const int* __restrict__ msk, float* __restrict__ out,
               float* __restrict__ entbuf) {
    const int pos = blockIdx.x;
    const int t = threadIdx.x;
    const float* st = stats + (size_t)pos * VSPLIT * 8;

    // redundant uniform combine on all threads (scalar-cached)
    float m1 = -1e30f, sA = 0.0f, sB = 0.0f, m2g = -1e30f;
    float bestv = -1e30f; int besti = 0;
    #pragma unroll
    for (int p = 0; p < VSPLIT; ++p) {
        const float* s = st + p * 8;
        float om = s[0], oA = s[1], oB = s[2];
        float mn = fmaxf(m1, om);
        float ea = __expf(m1 - mn), eb = __expf(om - mn);
        sB = (sB + sA * (m1 - mn)) * ea + (oB + oA * (om - mn)) * eb;
        sA = sA * ea + oA * eb;
        m1 = mn;
        m2g = fmaxf(m2g, s[3]);
        float av = s[5];
        if (av > bestv) { bestv = av; besti = __float_as_int(s[6]); }  // split order = index order
    }
    float beta[VSPLIT];
    float s2g = 0.0f;
    #pragma unroll
    for (int p = 0; p < VSPLIT; ++p) {
        beta[p] = __expf(st[p*8 + 3] - m2g);
        s2g += st[p*8 + 4] * beta[p];
    }

    const int iw = inp[pos];
    const bool mk = msk[pos] != 0;
    const bool safe = besti != iw;

    if (t == 0) {
        int obf = mk ? (safe ? besti : 0) : iw;
        out[pos] = (float)obf;
        float ent = sB / sA - logf(sA);       // sum lp*exp(lp), shift-invariant
        entbuf[pos] = mk ? ent : 0.0f;
    }
    if (t < D) {
        float e = 0.0f;
        const float* ep = Epart + (size_t)pos * VSPLIT * D + t;
        #pragma unroll
        for (int p = 0; p < VSPLIT; ++p) e += ep[(size_t)p * D] * beta[p];
        e /= s2g;                              // sampled_emb[t]
        float val;
        if (mk) val = safe ? e : W[t];         // W[0][t] = unk_emb
        else    val = W[(size_t)iw * D + t];   // base_emb
        out[P_TOT + (size_t)pos * D + t] = val;
    }
}

// ---------------------------------------------------------------------------
// Kernel 3: ent_loss scalar
// ---------------------------------------------------------------------------
__global__ __launch_bounds__(256)
void k_final(const float* __restrict__ entbuf, const int* __restrict__ msk,
             float* __restrict__ out) {
    __shared__ float se[4], sm[4];
    const int t = threadIdx.x;
    float e = 0.0f, m = 0.0f;
    for (int i = t; i < P_TOT; i += 256) {
        e += entbuf[i];
        m += (float)msk[i];
    }
    #pragma unroll
    for (int k = 32; k >= 1; k >>= 1) {
        e += __shfl_down(e, k, 64);
        m += __shfl_down(m, k, 64);
    }
    if ((t & 63) == 0) { se[t >> 6] = e; sm[t >> 6] = m; }
    __syncthreads();
    if (t == 0) {
        float te = se[0] + se[1] + se[2] + se[3];
        float tm = sm[0] + sm[1] + sm[2] + sm[3];
        out[P_TOT + (size_t)P_TOT * D] = te / (tm * (float)V);
    }
}

// ---------------------------------------------------------------------------
extern "C" void kernel_launch(void* const* d_in, const int* in_sizes, int n_in,
                              void* d_out, int out_size, void* d_ws, size_t ws_size,
                              hipStream_t stream) {
    const float* logits = (const float*)d_in[0];
    const float* gum    = (const float*)d_in[1];
    const int*   inp    = (const int*)d_in[2];
    const int*   msk    = (const int*)d_in[3];
    const float* W      = (const float*)d_in[4];
    float* out = (float*)d_out;

    char* ws = (char*)d_ws;
    unsigned short* Wtp = (unsigned short*)ws;            // 10*50*8704*2 = 8,704,000 B
    float* Epart  = (float*)(ws + 8704000);               // 2048*10*100*4 = 8,192,000 B
    float* stats  = (float*)(ws + 16896000);              // 2048*10*8*4  =   655,360 B
    float* entbuf = (float*)(ws + 17551360);              // 2048*4       =     8,192 B

    k_prep<<<dim3(NCHUNK, VSPLIT), 256, 0, stream>>>(W, Wtp);
    k_main<<<NSTILE * VSPLIT, 256, 0, stream>>>(logits, gum, Wtp, Epart, stats);
    k_combine<<<P_TOT, 128, 0, stream>>>(stats, Epart, W, inp, msk, out, entbuf);
    k_final<<<1, 256, 0, stream>>>(entbuf, msk, out);
}